// Round 1
// baseline (189.321 us; speedup 1.0000x reference)
//
#include <hip/hip_runtime.h>

// GCN mean-aggregator: out[i] = mean(features[nodes[i]], features[neigh_idx[i, 0..31]])
// V=100000, D=128, B=50000, K=32.
// One 64-lane wave per output row; each lane owns 2 columns (float2).
// Each gather load = 64 lanes x 8B = 512B = one full feature row, coalesced.

#define FEAT_D 128
#define NUM_K 32

__global__ __launch_bounds__(256) void gcn_agg_kernel(
    const float* __restrict__ features,
    const int*   __restrict__ nodes,
    const int*   __restrict__ neigh,
    float*       __restrict__ out,
    int n_rows)
{
    const int wave = threadIdx.x >> 6;            // 0..3
    const int lane = threadIdx.x & 63;            // 0..63
    const int row  = blockIdx.x * 4 + wave;
    if (row >= n_rows) return;

    float2 acc = make_float2(0.f, 0.f);

    // self node
    {
        const int idx = nodes[row];
        const float2* p = reinterpret_cast<const float2*>(features + (size_t)idx * FEAT_D);
        float2 v = p[lane];
        acc.x += v.x; acc.y += v.y;
    }

    // 32 sampled neighbors (index loads are wave-uniform -> scalar loads)
    const int* nrow = neigh + (size_t)row * NUM_K;
#pragma unroll
    for (int k = 0; k < NUM_K; ++k) {
        const int idx = nrow[k];
        const float2* p = reinterpret_cast<const float2*>(features + (size_t)idx * FEAT_D);
        float2 v = p[lane];
        acc.x += v.x; acc.y += v.y;
    }

    const float scale = 1.0f / 33.0f;
    float2 r = make_float2(acc.x * scale, acc.y * scale);
    reinterpret_cast<float2*>(out + (size_t)row * FEAT_D)[lane] = r;
}

extern "C" void kernel_launch(void* const* d_in, const int* in_sizes, int n_in,
                              void* d_out, int out_size, void* d_ws, size_t ws_size,
                              hipStream_t stream)
{
    const float* features = (const float*)d_in[0];   // [V, 128] fp32
    const int*   nodes    = (const int*)d_in[1];     // [B] int32
    const int*   neigh    = (const int*)d_in[2];     // [B, 32] int32
    float*       out      = (float*)d_out;           // [B, 128] fp32

    const int n_rows = in_sizes[1];                  // B = 50000
    const int rows_per_block = 4;                    // 4 waves x 1 row
    const int grid = (n_rows + rows_per_block - 1) / rows_per_block;

    gcn_agg_kernel<<<grid, 256, 0, stream>>>(features, nodes, neigh, out, n_rows);
}